// Round 8
// baseline (492.070 us; speedup 1.0000x reference)
//
#include <hip/hip_runtime.h>
#include <cstdint>

typedef unsigned short u16;
typedef unsigned long long u64;
typedef short short8 __attribute__((ext_vector_type(8)));
typedef float f32x4 __attribute__((ext_vector_type(4)));

#define D_DIM 192
#define M_PROT 128
#define KCOLS 256
#define GRID_P 256      // pass1: 1024-thr blocks -> 1/CU; grid = CU count
#define GRID_SL 2048    // sink: 256-thr blocks
#define GRID_P4 2048    // pass4: 256-thr blocks
#define BLK 1024
#define CHUNK_ROWS 64
#define SSLAB_ROWS 32   // sink slab (2 rows/thread)
#define P4SLAB_ROWS 32  // pass4 slab (2 rows/thread)
#define XSTRIDE 200   // u16 per x-row in LDS; 100 dwords -> 2-way banks on b128 reads (free)
#define NROWS_MAX 131072

// Materialized E = exp(20 * cos_sim), row-major [N][256]. 128 MiB static device
// allocation (graph-safe, no ws_size assumptions).
__device__ float Ebuf[(size_t)NROWS_MAX * KCOLS];
// Device-wide column accumulator + completion tickets (self-resetting: zero
// before and after every dispatch, so graph replay / rocprof replay are safe).
__device__ float Gacc[KCOLS];
__device__ int Cnt[4];
// Per-block local-argmax "last row index" candidates (merged in final_local).
__device__ int Bbuf[(size_t)GRID_P4 * M_PROT];

__device__ __forceinline__ float newton_rsqrt(float ss) {
    float m = fmaxf(ss, 1e-12f);
    float r = rsqrtf(m);
    r = r * (1.5f - 0.5f * m * r * r);
    return r;
}
__device__ __forceinline__ float fast_rcp(float x) {
    float r = __builtin_amdgcn_rcpf(x);
    return r * (2.0f - x * r);
}
// split fp32 -> bf16 hi (RNE) + bf16 lo (trunc of exact residual)
__device__ __forceinline__ void split1(float f, uint32_t& h, uint32_t& l) {
    uint32_t u = __float_as_uint(f);
    uint32_t uh = (u + 0x7FFFu + ((u >> 16) & 1u)) & 0xFFFF0000u;
    h = uh >> 16;
    l = __float_as_uint(f - __uint_as_float(uh)) >> 16;
}

// ---------------------------------------------------------------------------
__global__ void prep_kern(const float* __restrict__ lp, const float* __restrict__ gp,
                          u16* __restrict__ phi, u16* __restrict__ plo,
                          float* __restrict__ invnp) {
    int r = blockIdx.x, j = threadIdx.x;  // 256 x 64
    const float* src = (r < M_PROT) ? (lp + r * D_DIM) : (gp + (r - M_PROT) * D_DIM);
    float ss = 0.0f;
    for (int c = j; c < D_DIM; c += 64) {
        float f = src[c];
        ss = fmaf(f, f, ss);
        uint32_t h, l;
        split1(f, h, l);
        phi[r * D_DIM + c] = (u16)h;
        plo[r * D_DIM + c] = (u16)l;
    }
#pragma unroll
    for (int m = 1; m <= 32; m <<= 1) ss += __shfl_xor(ss, m);
    if (j == 0) invnp[r] = newton_rsqrt(ss);
}

// ---------------------------------------------------------------------------
__global__ __launch_bounds__(384) void glu_kern(const float* __restrict__ gp,
                                                const float* __restrict__ W,
                                                const float* __restrict__ b,
                                                float* __restrict__ gated) {
    __shared__ float grow[D_DIM];
    __shared__ float lin[2 * D_DIM];
    int m = blockIdx.x, j = threadIdx.x;
    if (j < D_DIM) grow[j] = gp[m * D_DIM + j];
    __syncthreads();
    float a = b[j];
    for (int k = 0; k < D_DIM; k++) a = fmaf(grow[k], W[k * 2 * D_DIM + j], a);
    lin[j] = a;
    __syncthreads();
    if (j < D_DIM) {
        float g = lin[j] * (1.0f / (1.0f + __expf(-lin[j + D_DIM])));
        gated[m * D_DIM + j] = g;
    }
}

// ---------------------------------------------------------------------------
// Pass 1: MFMA similarity + E = exp(20*sim), stored to Ebuf, fused with the
// first Sinkhorn colsum (Gacc atomics) and last-block g1 computation.
__global__ __launch_bounds__(BLK, 4) void pass1_kern(
    const float* __restrict__ x, const uint4* __restrict__ phiv, const uint4* __restrict__ plov,
    const float* __restrict__ invnp, float* __restrict__ outg, int nchunks) {
    __shared__ u16 xhiS[2][CHUNK_ROWS * XSTRIDE];
    __shared__ u16 xloS[2][CHUNK_ROWS * XSTRIDE];
    __shared__ float xnv[2][CHUNK_ROWS];    // per-row inverse norm (rsqrt hoisted)
    __shared__ float rsum[3][CHUNK_ROWS];   // 3 parities: zero/accum/read barrier-separated
    __shared__ int lastFlag;

    const int tid = threadIdx.x;
    const int lane = tid & 63;
    const int wave = tid >> 6;        // 0..15: proto col-tile
    const int quad = lane >> 4;
    const int lcol = lane & 15;
    const int srow = tid >> 4;        // staging: row 0..63
    const int scg = tid & 15;         // staging: col-group (12 floats)

    // --- B fragments in registers: this wave's 16 proto cols, all K, hi+lo ---
    uint4 Bhi[6], Blo[6];
    {
        int prow = wave * 16 + lcol;
#pragma unroll
        for (int kk = 0; kk < 6; kk++) {
            int idx = prow * 24 + kk * 4 + quad;
            Bhi[kk] = phiv[idx];
            Blo[kk] = plov[idx];
        }
    }
    // fold 20 * log2(e) into the proto inv-norm: E = exp2(a * invnx * pnf20l2)
    const float pnf20l2 = invnp[wave * 16 + lcol] * 28.853900817779268f;
    float colpart = 0.0f;

    // prefetch chunk 0: 3 float4 = 12 contiguous cols of row srow
    float4 st[3];
    int chunk = blockIdx.x;
    if (chunk < nchunks) {
        const float4* src = (const float4*)(x + (size_t)chunk * CHUNK_ROWS * D_DIM +
                                            srow * D_DIM + scg * 12);
#pragma unroll
        for (int j = 0; j < 3; j++) st[j] = src[j];
    }

    f32x4 Ep[4];   // previous chunk's E (deferred epilogue)
    int it = 0;
    for (; chunk < nchunks; chunk += gridDim.x, it++) {
        const int b = it & 1;    // LDS staging buffer
        const int p = it % 3;    // rsum parity for THIS chunk
        if (tid < CHUNK_ROWS) rsum[p][tid] = 0.0f;
        {
            float ssq = 0.0f;
            u16* bh = xhiS[b] + srow * XSTRIDE + scg * 12;
            u16* bl = xloS[b] + srow * XSTRIDE + scg * 12;
#pragma unroll
            for (int j = 0; j < 3; j++) {
                float4 v = st[j];
                ssq = fmaf(v.x, v.x, ssq);
                ssq = fmaf(v.y, v.y, ssq);
                ssq = fmaf(v.z, v.z, ssq);
                ssq = fmaf(v.w, v.w, ssq);
                uint32_t h0, l0, h1, l1, h2, l2, h3, l3;
                split1(v.x, h0, l0); split1(v.y, h1, l1);
                split1(v.z, h2, l2); split1(v.w, h3, l3);
                uint2 hp = {h0 | (h1 << 16), h2 | (h3 << 16)};
                uint2 lq = {l0 | (l1 << 16), l2 | (l3 << 16)};
                *(uint2*)(bh + j * 4) = hp;
                *(uint2*)(bl + j * 4) = lq;
            }
            ssq += __shfl_xor(ssq, 1);
            ssq += __shfl_xor(ssq, 2);
            ssq += __shfl_xor(ssq, 4);
            ssq += __shfl_xor(ssq, 8);
            if (scg == 0) xnv[b][srow] = newton_rsqrt(ssq);
        }
        {   // prefetch next chunk while this one computes
            int nc = chunk + gridDim.x;
            if (nc < nchunks) {
                const float4* src = (const float4*)(x + (size_t)nc * CHUNK_ROWS * D_DIM +
                                                    srow * D_DIM + scg * 12);
#pragma unroll
                for (int j = 0; j < 3; j++) st[j] = src[j];
            }
        }
        __syncthreads();  // single barrier: staging(b) visible; rsum[(it-1)%3] complete

        // --- deferred colsum epilogue for chunk it-1 ---
        if (it > 0) {
            const int pp = (p + 2) % 3;  // == (it-1)%3
#pragma unroll
            for (int s = 0; s < 4; s++) {
                const int rowb = s * 16 + quad * 4;
#pragma unroll
                for (int r = 0; r < 4; r++)
                    colpart = fmaf(Ep[s][r], fast_rcp(rsum[pp][rowb + r]), colpart);
            }
        }

        f32x4 E[4];
#pragma unroll
        for (int s = 0; s < 4; s++) {
            f32x4 a0 = {}, a1 = {};
#pragma unroll
            for (int kk = 0; kk < 6; kk++) {
                int off = (s * 16 + lcol) * XSTRIDE + kk * 32 + quad * 8;
                uint4 hraw = *(const uint4*)(xhiS[b] + off);
                uint4 lraw = *(const uint4*)(xloS[b] + off);
                short8 ah = __builtin_bit_cast(short8, hraw);
                short8 al = __builtin_bit_cast(short8, lraw);
                short8 bh = __builtin_bit_cast(short8, Bhi[kk]);
                short8 bl = __builtin_bit_cast(short8, Blo[kk]);
                if (kk & 1) {
                    a1 = __builtin_amdgcn_mfma_f32_16x16x32_bf16(ah, bh, a1, 0, 0, 0);
                    a1 = __builtin_amdgcn_mfma_f32_16x16x32_bf16(ah, bl, a1, 0, 0, 0);
                    a1 = __builtin_amdgcn_mfma_f32_16x16x32_bf16(al, bh, a1, 0, 0, 0);
                } else {
                    a0 = __builtin_amdgcn_mfma_f32_16x16x32_bf16(ah, bh, a0, 0, 0, 0);
                    a0 = __builtin_amdgcn_mfma_f32_16x16x32_bf16(ah, bl, a0, 0, 0, 0);
                    a0 = __builtin_amdgcn_mfma_f32_16x16x32_bf16(al, bh, a0, 0, 0, 0);
                }
            }
            const int rowb = s * 16 + quad * 4;
#pragma unroll
            for (int r = 0; r < 4; r++)
                E[s][r] = exp2f((a0[r] + a1[r]) * xnv[b][rowb + r] * pnf20l2);
            {
                float* eb = Ebuf + ((size_t)chunk * CHUNK_ROWS + rowb) * KCOLS +
                            (wave * 16 + lcol);
#pragma unroll
                for (int r = 0; r < 4; r++) eb[r * KCOLS] = E[s][r];
            }
#pragma unroll
            for (int r = 0; r < 4; r++) {
                float pe = E[s][r];
                pe += __shfl_xor(pe, 1);
                pe += __shfl_xor(pe, 2);
                pe += __shfl_xor(pe, 4);
                pe += __shfl_xor(pe, 8);
                if (lcol == 0) atomicAdd(&rsum[p][rowb + r], pe);
            }
        }
#pragma unroll
        for (int s = 0; s < 4; s++) Ep[s] = E[s];
    }

    // final deferred epilogue for the last chunk
    __syncthreads();
    {
        const int pl = (it + 2) % 3;  // == (it-1)%3
#pragma unroll
        for (int s = 0; s < 4; s++) {
            const int rowb = s * 16 + quad * 4;
#pragma unroll
            for (int r = 0; r < 4; r++)
                colpart = fmaf(Ep[s][r], fast_rcp(rsum[pl][rowb + r]), colpart);
        }
    }

    colpart += __shfl_xor(colpart, 16);
    colpart += __shfl_xor(colpart, 32);
    if (lane < 16) atomicAdd(&Gacc[wave * 16 + lcol], colpart);
    __syncthreads();  // all this block's Gacc atomics drained (vmcnt before barrier)
    if (tid == 0) {
        __threadfence();  // release: make our accumulation device-visible
        lastFlag = (atomicAdd(&Cnt[0], 1) == (int)gridDim.x - 1);
    }
    __syncthreads();
    if (lastFlag) {
        __threadfence();  // acquire
        if (tid < KCOLS) {
            float v = atomicAdd(&Gacc[tid], 0.0f);  // coherent read
            outg[tid] = 1.0f / v;
            atomicExch(&Gacc[tid], 0.0f);           // self-reset
        }
        if (tid == 0) atomicExch(&Cnt[0], 0);
    }
}

// ---------------------------------------------------------------------------
// Sinkhorn iteration, 32-row slabs, 2 rows/thread; per-block LDS merge, then
// Gacc atomics; last block computes outg = 1/colsum and self-resets.
__global__ __launch_bounds__(256) void sink_slab(const float* __restrict__ w,
                                                 float* __restrict__ outg,
                                                 int cid, int nslabs) {
    __shared__ float acc[KCOLS];
    __shared__ int lastFlag;
    const int tid = threadIdx.x;
    const int cg = tid & 15;
    acc[tid] = 0.0f;

    float4 wv[4];
    {
        const float4* wvp = (const float4*)w;
#pragma unroll
        for (int k = 0; k < 4; k++) wv[k] = wvp[cg * 4 + k];
    }
    float4 cp[4];
#pragma unroll
    for (int k = 0; k < 4; k++) { cp[k].x = 0.f; cp[k].y = 0.f; cp[k].z = 0.f; cp[k].w = 0.f; }

    for (int slab = blockIdx.x; slab < nslabs; slab += gridDim.x) {
        const float* base = Ebuf + (size_t)slab * SSLAB_ROWS * KCOLS;
        const float4* s0 = (const float4*)base + tid * 4;
        const float4* s1 = (const float4*)(base + 16 * KCOLS) + tid * 4;
        float4 sa[4], sb[4];
#pragma unroll
        for (int k = 0; k < 4; k++) sa[k] = s0[k];
#pragma unroll
        for (int k = 0; k < 4; k++) sb[k] = s1[k];

        float rs0 = 0.0f, rs1 = 0.0f;
#pragma unroll
        for (int k = 0; k < 4; k++) {
            rs0 = fmaf(sa[k].x, wv[k].x, rs0);
            rs0 = fmaf(sa[k].y, wv[k].y, rs0);
            rs0 = fmaf(sa[k].z, wv[k].z, rs0);
            rs0 = fmaf(sa[k].w, wv[k].w, rs0);
            rs1 = fmaf(sb[k].x, wv[k].x, rs1);
            rs1 = fmaf(sb[k].y, wv[k].y, rs1);
            rs1 = fmaf(sb[k].z, wv[k].z, rs1);
            rs1 = fmaf(sb[k].w, wv[k].w, rs1);
        }
        rs0 += __shfl_xor(rs0, 1);
        rs1 += __shfl_xor(rs1, 1);
        rs0 += __shfl_xor(rs0, 2);
        rs1 += __shfl_xor(rs1, 2);
        rs0 += __shfl_xor(rs0, 4);
        rs1 += __shfl_xor(rs1, 4);
        rs0 += __shfl_xor(rs0, 8);
        rs1 += __shfl_xor(rs1, 8);
        const float rv0 = fast_rcp(rs0);
        const float rv1 = fast_rcp(rs1);
#pragma unroll
        for (int k = 0; k < 4; k++) {
            cp[k].x = fmaf(sa[k].x, rv0, cp[k].x);
            cp[k].y = fmaf(sa[k].y, rv0, cp[k].y);
            cp[k].z = fmaf(sa[k].z, rv0, cp[k].z);
            cp[k].w = fmaf(sa[k].w, rv0, cp[k].w);
            cp[k].x = fmaf(sb[k].x, rv1, cp[k].x);
            cp[k].y = fmaf(sb[k].y, rv1, cp[k].y);
            cp[k].z = fmaf(sb[k].z, rv1, cp[k].z);
            cp[k].w = fmaf(sb[k].w, rv1, cp[k].w);
        }
    }

    __syncthreads();  // acc init visible
#pragma unroll
    for (int k = 0; k < 4; k++) {
        atomicAdd(&acc[cg * 16 + k * 4 + 0], cp[k].x);
        atomicAdd(&acc[cg * 16 + k * 4 + 1], cp[k].y);
        atomicAdd(&acc[cg * 16 + k * 4 + 2], cp[k].z);
        atomicAdd(&acc[cg * 16 + k * 4 + 3], cp[k].w);
    }
    __syncthreads();
    atomicAdd(&Gacc[tid], acc[tid]);
    __syncthreads();
    if (tid == 0) {
        __threadfence();
        lastFlag = (atomicAdd(&Cnt[cid], 1) == (int)gridDim.x - 1);
    }
    __syncthreads();
    if (lastFlag) {
        __threadfence();
        float v = atomicAdd(&Gacc[tid], 0.0f);
        outg[tid] = 1.0f / v;
        atomicExch(&Gacc[tid], 0.0f);
        if (tid == 0) atomicExch(&Cnt[cid], 0);
    }
}

// ---------------------------------------------------------------------------
// Final pass: 32-row slabs, 2 rows/thread in the argmax phase (8 float4 in
// flight), identical u64 tie-break keys; per-block Bbuf (no global atomics);
// GLU mix + L2-normalize epilogue, 8 rows/wave.
__global__ __launch_bounds__(256) void pass4_slab(const float* __restrict__ g3,
                                                  const float* __restrict__ x,
                                                  const float* __restrict__ gated,
                                                  float* __restrict__ outp, int nslabs) {
    __shared__ u64 bestL[2][P4SLAB_ROWS];
    __shared__ u64 bestG[2][P4SLAB_ROWS];
    __shared__ int blkBest[M_PROT];

    const int tid = threadIdx.x;
    const int lane = tid & 63;
    const int wave = tid >> 6;  // 0..3
    const int r16 = tid >> 4;   // 0..15
    const int cg = tid & 15;    // col-group: cols cg*16..cg*16+15

    if (tid < M_PROT) blkBest[tid] = -1;

    float4 cf[4];
    {
        const float4* g3v = (const float4*)g3;
#pragma unroll
        for (int k = 0; k < 4; k++) cf[k] = g3v[cg * 4 + k];
    }
    __syncthreads();  // blkBest init visible

    int it = 0;
    for (int slab = blockIdx.x; slab < nslabs; slab += gridDim.x, it++) {
        const int p = it & 1;
        const float* base = Ebuf + (size_t)slab * P4SLAB_ROWS * KCOLS;
        const float4* s0 = (const float4*)base + tid * 4;
        const float4* s1 = (const float4*)(base + 16 * KCOLS) + tid * 4;
        float4 sa[4], sb[4];
#pragma unroll
        for (int k = 0; k < 4; k++) sa[k] = s0[k];
#pragma unroll
        for (int k = 0; k < 4; k++) sb[k] = s1[k];

        u64 keyA = 0, keyB = 0;
        const int cb = cg * 16;
#pragma unroll
        for (int k = 0; k < 4; k++) {
            const float* ea = (const float*)&sa[k];
            const float* eb = (const float*)&sb[k];
            const float* ck = (const float*)&cf[k];
#pragma unroll
            for (int j = 0; j < 4; j++) {
                float va = ea[j] * ck[j];
                float vb = eb[j] * ck[j];
                u64 ka = ((u64)__float_as_uint(va) << 32) | (u64)(255 - (cb + k * 4 + j));
                u64 kb = ((u64)__float_as_uint(vb) << 32) | (u64)(255 - (cb + k * 4 + j));
                if (ka > keyA) keyA = ka;
                if (kb > keyB) keyB = kb;
            }
        }
        // reduce within 8-lane half-group (cg 0..7 = local cols, 8..15 = global)
        {
            u64 ok;
            ok = __shfl_xor((unsigned long long)keyA, 1); if (ok > keyA) keyA = ok;
            ok = __shfl_xor((unsigned long long)keyB, 1); if (ok > keyB) keyB = ok;
            ok = __shfl_xor((unsigned long long)keyA, 2); if (ok > keyA) keyA = ok;
            ok = __shfl_xor((unsigned long long)keyB, 2); if (ok > keyB) keyB = ok;
            ok = __shfl_xor((unsigned long long)keyA, 4); if (ok > keyA) keyA = ok;
            ok = __shfl_xor((unsigned long long)keyB, 4); if (ok > keyB) keyB = ok;
        }
        if ((lane & 7) == 0) {
            if (cg < 8) { bestL[p][r16] = keyA; bestL[p][r16 + 16] = keyB; }
            else        { bestG[p][r16] = keyA; bestG[p][r16 + 16] = keyB; }
        }
        __syncthreads();  // bests visible; parity-p slots not rewritten until
                          // after the NEXT iteration's barrier

        if (tid < P4SLAB_ROWS) {
            int colL = 255 - (int)(bestL[p][tid] & 0xFFFFFFFFull);
            atomicMax(&blkBest[colL], slab * P4SLAB_ROWS + tid);  // LDS atomic
        }
#pragma unroll
        for (int rr = 0; rr < 8; rr++) {
            const int row = wave * 8 + rr;
            const int grow = slab * P4SLAB_ROWS + row;
            const float* xr = x + (size_t)grow * D_DIM;
            float x0 = xr[lane];
            float x1 = xr[lane + 64];
            float x2 = xr[lane + 128];
            const int ga = (255 - (int)(bestG[p][row] & 0xFFFFFFFFull)) - 128;
            const float* gr = gated + ga * D_DIM;
            float v0 = 0.5f * (gr[lane] + x0);
            float v1 = 0.5f * (gr[lane + 64] + x1);
            float v2 = 0.5f * (gr[lane + 128] + x2);
            float ss = v0 * v0;
            ss = fmaf(v1, v1, ss);
            ss = fmaf(v2, v2, ss);
            ss += __shfl_xor(ss, 1);
            ss += __shfl_xor(ss, 2);
            ss += __shfl_xor(ss, 4);
            ss += __shfl_xor(ss, 8);
            ss += __shfl_xor(ss, 16);
            ss += __shfl_xor(ss, 32);
            const float sc = newton_rsqrt(ss);
            float* orow = outp + (size_t)grow * D_DIM;
            orow[lane] = v0 * sc;
            orow[lane + 64] = v1 * sc;
            orow[lane + 128] = v2 * sc;
        }
    }

    __syncthreads();
    if (tid < M_PROT) Bbuf[(size_t)blockIdx.x * M_PROT + tid] = blkBest[tid];
}

// ---------------------------------------------------------------------------
// Merge per-block argmax candidates (max row index per proto) + EMA update.
__global__ __launch_bounds__(256) void final_local(const float* __restrict__ lp,
                                                   const float* __restrict__ x,
                                                   float* __restrict__ outL) {
    __shared__ int red[4];
    const int m = blockIdx.x;   // 128
    const int tid = threadIdx.x;
    const int lane = tid & 63;
    const int w = tid >> 6;
    int v = -1;
    for (int b = tid; b < GRID_P4; b += 256) {
        int c = Bbuf[(size_t)b * M_PROT + m];
        if (c > v) v = c;
    }
#pragma unroll
    for (int s = 1; s <= 32; s <<= 1) {
        int o = __shfl_xor(v, s);
        if (o > v) v = o;
    }
    if (lane == 0) red[w] = v;
    __syncthreads();
    int idx = max(max(red[0], red[1]), max(red[2], red[3]));
    if (tid < D_DIM) {
        float val = lp[m * D_DIM + tid];
        if (idx >= 0) val = 0.96f * val + (float)(1.0 - 0.96) * x[(size_t)idx * D_DIM + tid];
        outL[m * D_DIM + tid] = val;
    }
}

// ---------------------------------------------------------------------------
extern "C" void kernel_launch(void* const* d_in, const int* in_sizes, int n_in,
                              void* d_out, int out_size, void* d_ws, size_t ws_size,
                              hipStream_t stream) {
    const float* x = (const float*)d_in[0];
    const float* lp = (const float*)d_in[1];
    const float* gp = (const float*)d_in[2];
    const float* W = (const float*)d_in[3];
    const float* b = (const float*)d_in[4];
    float* out = (float*)d_out;
    const int nrows = in_sizes[0] / D_DIM;    // 131072
    const int nchunks = nrows / CHUNK_ROWS;   // 2048
    const int nslabsS = nrows / SSLAB_ROWS;   // 4096
    const int nslabs4 = nrows / P4SLAB_ROWS;  // 4096

    char* wsb = (char*)d_ws;
    float* invnp = (float*)(wsb + 0);
    float* g1 = (float*)(wsb + 1024);
    float* g2 = (float*)(wsb + 2048);
    float* g3 = (float*)(wsb + 3072);
    float* gated = (float*)(wsb + 8192);      // 128*192 f
    u16* phi = (u16*)(wsb + 106496);          // 256*192 u16
    u16* plo = (u16*)(wsb + 204800);          // 256*192 u16

    const uint4* phiv = (const uint4*)phi;
    const uint4* plov = (const uint4*)plo;

    prep_kern<<<256, 64, 0, stream>>>(lp, gp, phi, plo, invnp);
    glu_kern<<<128, 384, 0, stream>>>(gp, W, b, gated);
    pass1_kern<<<GRID_P, BLK, 0, stream>>>(x, phiv, plov, invnp, g1, nchunks);
    sink_slab<<<GRID_SL, 256, 0, stream>>>(g1, g2, 1, nslabsS);
    sink_slab<<<GRID_SL, 256, 0, stream>>>(g2, g3, 2, nslabsS);
    pass4_slab<<<GRID_P4, 256, 0, stream>>>(g3, x, gated, out, nslabs4);
    final_local<<<128, 256, 0, stream>>>(lp, x, out + (size_t)nrows * D_DIM);
}

// Round 9
// 422.024 us; speedup vs baseline: 1.1660x; 1.1660x over previous
//
#include <hip/hip_runtime.h>
#include <cstdint>

typedef unsigned short u16;
typedef unsigned long long u64;
typedef short short8 __attribute__((ext_vector_type(8)));
typedef float f32x4 __attribute__((ext_vector_type(4)));

#define D_DIM 192
#define M_PROT 128
#define KCOLS 256
#define GRID_P 256      // pass1: 1024-thr blocks -> 1/CU; grid = CU count
#define GRID_SL 2048    // slab kernels: 256-thr blocks
#define BLK 1024
#define CHUNK_ROWS 64
#define SSLAB_ROWS 32   // sink slab (2 rows/thread)
#define P4SLAB_ROWS 32  // pass4 slab (2 rows/thread)
#define XSTRIDE 200   // u16 per x-row in LDS; 100 dwords -> 2-way banks on b128 reads (free)
#define NROWS_MAX 131072
#define RED1_BLKS 64

// Materialized E = exp(20 * cos_sim), row-major [N][256]. 128 MiB static device
// allocation (graph-safe, no ws_size assumptions).
__device__ float Ebuf[(size_t)NROWS_MAX * KCOLS];
// Per-block column partials + two-stage reduce intermediate.
__device__ float Pbuf[(size_t)GRID_SL * KCOLS];
__device__ float Mbuf[(size_t)RED1_BLKS * KCOLS];
// Per-block local-argmax "last row index" candidates (merged in final_local).
__device__ int Bbuf[(size_t)GRID_SL * M_PROT];

__device__ __forceinline__ float newton_rsqrt(float ss) {
    float m = fmaxf(ss, 1e-12f);
    float r = rsqrtf(m);
    r = r * (1.5f - 0.5f * m * r * r);
    return r;
}
__device__ __forceinline__ float fast_rcp(float x) {
    float r = __builtin_amdgcn_rcpf(x);
    return r * (2.0f - x * r);
}
// split fp32 -> bf16 hi (RNE) + bf16 lo (trunc of exact residual)
__device__ __forceinline__ void split1(float f, uint32_t& h, uint32_t& l) {
    uint32_t u = __float_as_uint(f);
    uint32_t uh = (u + 0x7FFFu + ((u >> 16) & 1u)) & 0xFFFF0000u;
    h = uh >> 16;
    l = __float_as_uint(f - __uint_as_float(uh)) >> 16;
}

// ---------------------------------------------------------------------------
__global__ void prep_kern(const float* __restrict__ lp, const float* __restrict__ gp,
                          u16* __restrict__ phi, u16* __restrict__ plo,
                          float* __restrict__ invnp) {
    int r = blockIdx.x, j = threadIdx.x;  // 256 x 64
    const float* src = (r < M_PROT) ? (lp + r * D_DIM) : (gp + (r - M_PROT) * D_DIM);
    float ss = 0.0f;
    for (int c = j; c < D_DIM; c += 64) {
        float f = src[c];
        ss = fmaf(f, f, ss);
        uint32_t h, l;
        split1(f, h, l);
        phi[r * D_DIM + c] = (u16)h;
        plo[r * D_DIM + c] = (u16)l;
    }
#pragma unroll
    for (int m = 1; m <= 32; m <<= 1) ss += __shfl_xor(ss, m);
    if (j == 0) invnp[r] = newton_rsqrt(ss);
}

// ---------------------------------------------------------------------------
__global__ __launch_bounds__(384) void glu_kern(const float* __restrict__ gp,
                                                const float* __restrict__ W,
                                                const float* __restrict__ b,
                                                float* __restrict__ gated) {
    __shared__ float grow[D_DIM];
    __shared__ float lin[2 * D_DIM];
    int m = blockIdx.x, j = threadIdx.x;
    if (j < D_DIM) grow[j] = gp[m * D_DIM + j];
    __syncthreads();
    float a = b[j];
    for (int k = 0; k < D_DIM; k++) a = fmaf(grow[k], W[k * 2 * D_DIM + j], a);
    lin[j] = a;
    __syncthreads();
    if (j < D_DIM) {
        float g = lin[j] * (1.0f / (1.0f + __expf(-lin[j + D_DIM])));
        gated[m * D_DIM + j] = g;
    }
}

// ---------------------------------------------------------------------------
// Two-stage parallel column reduce: Pbuf[0..G) -> Mbuf[64] -> outf (1/x).
__global__ __launch_bounds__(256) void reduce1(int G) {
    int j = threadIdx.x;
    float s = 0.0f;
    for (int g = blockIdx.x; g < G; g += RED1_BLKS) s += Pbuf[(size_t)g * KCOLS + j];
    Mbuf[blockIdx.x * KCOLS + j] = s;
}
__global__ __launch_bounds__(256) void reduce2(float* __restrict__ outf) {
    int j = threadIdx.x;
    float s = 0.0f;
    for (int g = 0; g < RED1_BLKS; g++) s += Mbuf[g * KCOLS + j];
    outf[j] = 1.0f / s;
}

// ---------------------------------------------------------------------------
// Pass 1: MFMA similarity + E = exp(20*sim), stored to Ebuf, fused with the
// first Sinkhorn colsum. Single-barrier pipeline: double-buffered x staging,
// 3-parity rsum rotation, colsum epilogue deferred one iteration (Eprev).
__global__ __launch_bounds__(BLK, 4) void pass1_kern(
    const float* __restrict__ x, const uint4* __restrict__ phiv, const uint4* __restrict__ plov,
    const float* __restrict__ invnp, int nchunks) {
    __shared__ u16 xhiS[2][CHUNK_ROWS * XSTRIDE];
    __shared__ u16 xloS[2][CHUNK_ROWS * XSTRIDE];
    __shared__ float xnv[2][CHUNK_ROWS];    // per-row inverse norm (rsqrt hoisted)
    __shared__ float rsum[3][CHUNK_ROWS];   // 3 parities: zero/accum/read barrier-separated

    const int tid = threadIdx.x;
    const int lane = tid & 63;
    const int wave = tid >> 6;        // 0..15: proto col-tile
    const int quad = lane >> 4;
    const int lcol = lane & 15;
    const int srow = tid >> 4;        // staging: row 0..63
    const int scg = tid & 15;         // staging: col-group (12 floats)

    // --- B fragments in registers: this wave's 16 proto cols, all K, hi+lo ---
    uint4 Bhi[6], Blo[6];
    {
        int prow = wave * 16 + lcol;
#pragma unroll
        for (int kk = 0; kk < 6; kk++) {
            int idx = prow * 24 + kk * 4 + quad;
            Bhi[kk] = phiv[idx];
            Blo[kk] = plov[idx];
        }
    }
    // fold 20 * log2(e) into the proto inv-norm: E = exp2(a * invnx * pnf20l2)
    const float pnf20l2 = invnp[wave * 16 + lcol] * 28.853900817779268f;
    float colpart = 0.0f;

    // prefetch chunk 0: 3 float4 = 12 contiguous cols of row srow
    float4 st[3];
    int chunk = blockIdx.x;
    if (chunk < nchunks) {
        const float4* src = (const float4*)(x + (size_t)chunk * CHUNK_ROWS * D_DIM +
                                            srow * D_DIM + scg * 12);
#pragma unroll
        for (int j = 0; j < 3; j++) st[j] = src[j];
    }

    f32x4 Ep[4];   // previous chunk's E (deferred epilogue)
    int it = 0;
    for (; chunk < nchunks; chunk += gridDim.x, it++) {
        const int b = it & 1;    // LDS staging buffer
        const int p = it % 3;    // rsum parity for THIS chunk
        if (tid < CHUNK_ROWS) rsum[p][tid] = 0.0f;
        {
            float ssq = 0.0f;
            u16* bh = xhiS[b] + srow * XSTRIDE + scg * 12;
            u16* bl = xloS[b] + srow * XSTRIDE + scg * 12;
#pragma unroll
            for (int j = 0; j < 3; j++) {
                float4 v = st[j];
                ssq = fmaf(v.x, v.x, ssq);
                ssq = fmaf(v.y, v.y, ssq);
                ssq = fmaf(v.z, v.z, ssq);
                ssq = fmaf(v.w, v.w, ssq);
                uint32_t h0, l0, h1, l1, h2, l2, h3, l3;
                split1(v.x, h0, l0); split1(v.y, h1, l1);
                split1(v.z, h2, l2); split1(v.w, h3, l3);
                uint2 hp = {h0 | (h1 << 16), h2 | (h3 << 16)};
                uint2 lq = {l0 | (l1 << 16), l2 | (l3 << 16)};
                *(uint2*)(bh + j * 4) = hp;
                *(uint2*)(bl + j * 4) = lq;
            }
            ssq += __shfl_xor(ssq, 1);
            ssq += __shfl_xor(ssq, 2);
            ssq += __shfl_xor(ssq, 4);
            ssq += __shfl_xor(ssq, 8);
            if (scg == 0) xnv[b][srow] = newton_rsqrt(ssq);
        }
        {   // prefetch next chunk while this one computes
            int nc = chunk + gridDim.x;
            if (nc < nchunks) {
                const float4* src = (const float4*)(x + (size_t)nc * CHUNK_ROWS * D_DIM +
                                                    srow * D_DIM + scg * 12);
#pragma unroll
                for (int j = 0; j < 3; j++) st[j] = src[j];
            }
        }
        __syncthreads();  // single barrier: staging(b) visible; rsum[(it-1)%3] complete

        // --- deferred colsum epilogue for chunk it-1 ---
        if (it > 0) {
            const int pp = (p + 2) % 3;  // == (it-1)%3
#pragma unroll
            for (int s = 0; s < 4; s++) {
                const int rowb = s * 16 + quad * 4;
#pragma unroll
                for (int r = 0; r < 4; r++)
                    colpart = fmaf(Ep[s][r], fast_rcp(rsum[pp][rowb + r]), colpart);
            }
        }

        f32x4 E[4];
#pragma unroll
        for (int s = 0; s < 4; s++) {
            f32x4 a0 = {}, a1 = {};
#pragma unroll
            for (int kk = 0; kk < 6; kk++) {
                int off = (s * 16 + lcol) * XSTRIDE + kk * 32 + quad * 8;
                uint4 hraw = *(const uint4*)(xhiS[b] + off);
                uint4 lraw = *(const uint4*)(xloS[b] + off);
                short8 ah = __builtin_bit_cast(short8, hraw);
                short8 al = __builtin_bit_cast(short8, lraw);
                short8 bh = __builtin_bit_cast(short8, Bhi[kk]);
                short8 bl = __builtin_bit_cast(short8, Blo[kk]);
                if (kk & 1) {
                    a1 = __builtin_amdgcn_mfma_f32_16x16x32_bf16(ah, bh, a1, 0, 0, 0);
                    a1 = __builtin_amdgcn_mfma_f32_16x16x32_bf16(ah, bl, a1, 0, 0, 0);
                    a1 = __builtin_amdgcn_mfma_f32_16x16x32_bf16(al, bh, a1, 0, 0, 0);
                } else {
                    a0 = __builtin_amdgcn_mfma_f32_16x16x32_bf16(ah, bh, a0, 0, 0, 0);
                    a0 = __builtin_amdgcn_mfma_f32_16x16x32_bf16(ah, bl, a0, 0, 0, 0);
                    a0 = __builtin_amdgcn_mfma_f32_16x16x32_bf16(al, bh, a0, 0, 0, 0);
                }
            }
            const int rowb = s * 16 + quad * 4;
#pragma unroll
            for (int r = 0; r < 4; r++)
                E[s][r] = exp2f((a0[r] + a1[r]) * xnv[b][rowb + r] * pnf20l2);
            // store E tile to global (row-major [N][256]); fire-and-forget
            {
                float* eb = Ebuf + ((size_t)chunk * CHUNK_ROWS + rowb) * KCOLS +
                            (wave * 16 + lcol);
#pragma unroll
                for (int r = 0; r < 4; r++) eb[r * KCOLS] = E[s][r];
            }
#pragma unroll
            for (int r = 0; r < 4; r++) {
                float pe = E[s][r];
                pe += __shfl_xor(pe, 1);
                pe += __shfl_xor(pe, 2);
                pe += __shfl_xor(pe, 4);
                pe += __shfl_xor(pe, 8);
                if (lcol == 0) atomicAdd(&rsum[p][rowb + r], pe);
            }
        }
#pragma unroll
        for (int s = 0; s < 4; s++) Ep[s] = E[s];
    }

    // final deferred epilogue for the last chunk
    __syncthreads();
    {
        const int pl = (it + 2) % 3;  // == (it-1)%3
#pragma unroll
        for (int s = 0; s < 4; s++) {
            const int rowb = s * 16 + quad * 4;
#pragma unroll
            for (int r = 0; r < 4; r++)
                colpart = fmaf(Ep[s][r], fast_rcp(rsum[pl][rowb + r]), colpart);
        }
    }

    colpart += __shfl_xor(colpart, 16);
    colpart += __shfl_xor(colpart, 32);
    if (lane < 16) Pbuf[(size_t)blockIdx.x * KCOLS + wave * 16 + lcol] = colpart;
}

// ---------------------------------------------------------------------------
// Sinkhorn iteration, 32-row slabs, 2 rows/thread (8 loads in flight for ILP).
// Thread t owns rows (t>>4) and (t>>4)+16, cols (t&15)*16..+15.
__global__ __launch_bounds__(256) void sink_slab(const float* __restrict__ w,
                                                 int nslabs32) {
    __shared__ float acc[KCOLS];
    const int tid = threadIdx.x;
    const int cg = tid & 15;
    acc[tid] = 0.0f;

    float4 wv[4];
    {
        const float4* wvp = (const float4*)w;
#pragma unroll
        for (int k = 0; k < 4; k++) wv[k] = wvp[cg * 4 + k];
    }
    float4 cp[4];
#pragma unroll
    for (int k = 0; k < 4; k++) { cp[k].x = 0.f; cp[k].y = 0.f; cp[k].z = 0.f; cp[k].w = 0.f; }

    for (int slab = blockIdx.x; slab < nslabs32; slab += gridDim.x) {
        const float* base = Ebuf + (size_t)slab * SSLAB_ROWS * KCOLS;
        const float4* s0 = (const float4*)base + tid * 4;
        const float4* s1 = (const float4*)(base + 16 * KCOLS) + tid * 4;
        float4 sa[4], sb[4];
#pragma unroll
        for (int k = 0; k < 4; k++) sa[k] = s0[k];
#pragma unroll
        for (int k = 0; k < 4; k++) sb[k] = s1[k];

        float rs0 = 0.0f, rs1 = 0.0f;
#pragma unroll
        for (int k = 0; k < 4; k++) {
            rs0 = fmaf(sa[k].x, wv[k].x, rs0);
            rs0 = fmaf(sa[k].y, wv[k].y, rs0);
            rs0 = fmaf(sa[k].z, wv[k].z, rs0);
            rs0 = fmaf(sa[k].w, wv[k].w, rs0);
            rs1 = fmaf(sb[k].x, wv[k].x, rs1);
            rs1 = fmaf(sb[k].y, wv[k].y, rs1);
            rs1 = fmaf(sb[k].z, wv[k].z, rs1);
            rs1 = fmaf(sb[k].w, wv[k].w, rs1);
        }
        rs0 += __shfl_xor(rs0, 1);
        rs1 += __shfl_xor(rs1, 1);
        rs0 += __shfl_xor(rs0, 2);
        rs1 += __shfl_xor(rs1, 2);
        rs0 += __shfl_xor(rs0, 4);
        rs1 += __shfl_xor(rs1, 4);
        rs0 += __shfl_xor(rs0, 8);
        rs1 += __shfl_xor(rs1, 8);
        const float rv0 = fast_rcp(rs0);
        const float rv1 = fast_rcp(rs1);
#pragma unroll
        for (int k = 0; k < 4; k++) {
            cp[k].x = fmaf(sa[k].x, rv0, cp[k].x);
            cp[k].y = fmaf(sa[k].y, rv0, cp[k].y);
            cp[k].z = fmaf(sa[k].z, rv0, cp[k].z);
            cp[k].w = fmaf(sa[k].w, rv0, cp[k].w);
            cp[k].x = fmaf(sb[k].x, rv1, cp[k].x);
            cp[k].y = fmaf(sb[k].y, rv1, cp[k].y);
            cp[k].z = fmaf(sb[k].z, rv1, cp[k].z);
            cp[k].w = fmaf(sb[k].w, rv1, cp[k].w);
        }
    }

    __syncthreads();  // acc init visible
#pragma unroll
    for (int k = 0; k < 4; k++) {
        atomicAdd(&acc[cg * 16 + k * 4 + 0], cp[k].x);
        atomicAdd(&acc[cg * 16 + k * 4 + 1], cp[k].y);
        atomicAdd(&acc[cg * 16 + k * 4 + 2], cp[k].z);
        atomicAdd(&acc[cg * 16 + k * 4 + 3], cp[k].w);
    }
    __syncthreads();
    Pbuf[(size_t)blockIdx.x * KCOLS + tid] = acc[tid];
}

// ---------------------------------------------------------------------------
// Final pass: 32-row slabs, 2 rows/thread in the argmax phase (8 float4 in
// flight), identical u64 tie-break keys; per-block Bbuf (no global atomics);
// GLU mix + L2-normalize epilogue, 8 rows/wave.
__global__ __launch_bounds__(256) void pass4_slab(const float* __restrict__ g3,
                                                  const float* __restrict__ x,
                                                  const float* __restrict__ gated,
                                                  float* __restrict__ outp, int nslabs) {
    __shared__ u64 bestL[2][P4SLAB_ROWS];
    __shared__ u64 bestG[2][P4SLAB_ROWS];
    __shared__ int blkBest[M_PROT];

    const int tid = threadIdx.x;
    const int lane = tid & 63;
    const int wave = tid >> 6;  // 0..3
    const int r16 = tid >> 4;   // 0..15
    const int cg = tid & 15;    // col-group: cols cg*16..cg*16+15

    if (tid < M_PROT) blkBest[tid] = -1;

    float4 cf[4];
    {
        const float4* g3v = (const float4*)g3;
#pragma unroll
        for (int k = 0; k < 4; k++) cf[k] = g3v[cg * 4 + k];
    }
    __syncthreads();  // blkBest init visible

    int it = 0;
    for (int slab = blockIdx.x; slab < nslabs; slab += gridDim.x, it++) {
        const int p = it & 1;
        const float* base = Ebuf + (size_t)slab * P4SLAB_ROWS * KCOLS;
        const float4* s0 = (const float4*)base + tid * 4;
        const float4* s1 = (const float4*)(base + 16 * KCOLS) + tid * 4;
        float4 sa[4], sb[4];
#pragma unroll
        for (int k = 0; k < 4; k++) sa[k] = s0[k];
#pragma unroll
        for (int k = 0; k < 4; k++) sb[k] = s1[k];

        u64 keyA = 0, keyB = 0;
        const int cb = cg * 16;
#pragma unroll
        for (int k = 0; k < 4; k++) {
            const float* ea = (const float*)&sa[k];
            const float* eb = (const float*)&sb[k];
            const float* ck = (const float*)&cf[k];
#pragma unroll
            for (int j = 0; j < 4; j++) {
                float va = ea[j] * ck[j];
                float vb = eb[j] * ck[j];
                u64 ka = ((u64)__float_as_uint(va) << 32) | (u64)(255 - (cb + k * 4 + j));
                u64 kb = ((u64)__float_as_uint(vb) << 32) | (u64)(255 - (cb + k * 4 + j));
                if (ka > keyA) keyA = ka;
                if (kb > keyB) keyB = kb;
            }
        }
        // reduce within 8-lane half-group (cg 0..7 = local cols, 8..15 = global)
        {
            u64 ok;
            ok = __shfl_xor((unsigned long long)keyA, 1); if (ok > keyA) keyA = ok;
            ok = __shfl_xor((unsigned long long)keyB, 1); if (ok > keyB) keyB = ok;
            ok = __shfl_xor((unsigned long long)keyA, 2); if (ok > keyA) keyA = ok;
            ok = __shfl_xor((unsigned long long)keyB, 2); if (ok > keyB) keyB = ok;
            ok = __shfl_xor((unsigned long long)keyA, 4); if (ok > keyA) keyA = ok;
            ok = __shfl_xor((unsigned long long)keyB, 4); if (ok > keyB) keyB = ok;
        }
        if ((lane & 7) == 0) {
            if (cg < 8) { bestL[p][r16] = keyA; bestL[p][r16 + 16] = keyB; }
            else        { bestG[p][r16] = keyA; bestG[p][r16 + 16] = keyB; }
        }
        __syncthreads();  // bests visible; parity-p slots not rewritten until
                          // after the NEXT iteration's barrier

        if (tid < P4SLAB_ROWS) {
            int colL = 255 - (int)(bestL[p][tid] & 0xFFFFFFFFull);
            atomicMax(&blkBest[colL], slab * P4SLAB_ROWS + tid);  // LDS atomic
        }
#pragma unroll
        for (int rr = 0; rr < 8; rr++) {
            const int row = wave * 8 + rr;
            const int grow = slab * P4SLAB_ROWS + row;
            const float* xr = x + (size_t)grow * D_DIM;
            float x0 = xr[lane];
            float x1 = xr[lane + 64];
            float x2 = xr[lane + 128];
            const int ga = (255 - (int)(bestG[p][row] & 0xFFFFFFFFull)) - 128;
            const float* gr = gated + ga * D_DIM;
            float v0 = 0.5f * (gr[lane] + x0);
            float v1 = 0.5f * (gr[lane + 64] + x1);
            float v2 = 0.5f * (gr[lane + 128] + x2);
            float ss = v0 * v0;
            ss = fmaf(v1, v1, ss);
            ss = fmaf(v2, v2, ss);
            ss += __shfl_xor(ss, 1);
            ss += __shfl_xor(ss, 2);
            ss += __shfl_xor(ss, 4);
            ss += __shfl_xor(ss, 8);
            ss += __shfl_xor(ss, 16);
            ss += __shfl_xor(ss, 32);
            const float sc = newton_rsqrt(ss);
            float* orow = outp + (size_t)grow * D_DIM;
            orow[lane] = v0 * sc;
            orow[lane + 64] = v1 * sc;
            orow[lane + 128] = v2 * sc;
        }
    }

    __syncthreads();
    if (tid < M_PROT) Bbuf[(size_t)blockIdx.x * M_PROT + tid] = blkBest[tid];
}

// ---------------------------------------------------------------------------
// Merge per-block argmax candidates (max row index per proto) + EMA update.
__global__ __launch_bounds__(256) void final_local(const float* __restrict__ lp,
                                                   const float* __restrict__ x,
                                                   float* __restrict__ outL) {
    __shared__ int red[4];
    const int m = blockIdx.x;   // 128
    const int tid = threadIdx.x;
    const int lane = tid & 63;
    const int w = tid >> 6;
    int v = -1;
    for (int b = tid; b < GRID_SL; b += 256) {
        int c = Bbuf[(size_t)b * M_PROT + m];
        if (c > v) v = c;
    }
#pragma unroll
    for (int s = 1; s <= 32; s <<= 1) {
        int o = __shfl_xor(v, s);
        if (o > v) v = o;
    }
    if (lane == 0) red[w] = v;
    __syncthreads();
    int idx = max(max(red[0], red[1]), max(red[2], red[3]));
    if (tid < D_DIM) {
        float val = lp[m * D_DIM + tid];
        if (idx >= 0) val = 0.96f * val + (float)(1.0 - 0.96) * x[(size_t)idx * D_DIM + tid];
        outL[m * D_DIM + tid] = val;
    }
}

// ---------------------------------------------------------------------------
extern "C" void kernel_launch(void* const* d_in, const int* in_sizes, int n_in,
                              void* d_out, int out_size, void* d_ws, size_t ws_size,
                              hipStream_t stream) {
    const float* x = (const float*)d_in[0];
    const float* lp = (const float*)d_in[1];
    const float* gp = (const float*)d_in[2];
    const float* W = (const float*)d_in[3];
    const float* b = (const float*)d_in[4];
    float* out = (float*)d_out;
    const int nrows = in_sizes[0] / D_DIM;    // 131072
    const int nchunks = nrows / CHUNK_ROWS;   // 2048
    const int nslabsS = nrows / SSLAB_ROWS;   // 4096
    const int nslabs4 = nrows / P4SLAB_ROWS;  // 4096

    char* wsb = (char*)d_ws;
    float* invnp = (float*)(wsb + 0);
    float* g1 = (float*)(wsb + 1024);
    float* g2 = (float*)(wsb + 2048);
    float* g3 = (float*)(wsb + 3072);
    float* gated = (float*)(wsb + 8192);      // 128*192 f
    u16* phi = (u16*)(wsb + 106496);          // 256*192 u16
    u16* plo = (u16*)(wsb + 204800);          // 256*192 u16

    const uint4* phiv = (const uint4*)phi;
    const uint4* plov = (const uint4*)plo;

    prep_kern<<<256, 64, 0, stream>>>(lp, gp, phi, plo, invnp);
    glu_kern<<<128, 384, 0, stream>>>(gp, W, b, gated);
    pass1_kern<<<GRID_P, BLK, 0, stream>>>(x, phiv, plov, invnp, nchunks);
    reduce1<<<RED1_BLKS, 256, 0, stream>>>(GRID_P);
    reduce2<<<1, 256, 0, stream>>>(g1);
    sink_slab<<<GRID_SL, 256, 0, stream>>>(g1, nslabsS);
    reduce1<<<RED1_BLKS, 256, 0, stream>>>(GRID_SL);
    reduce2<<<1, 256, 0, stream>>>(g2);
    sink_slab<<<GRID_SL, 256, 0, stream>>>(g2, nslabsS);
    reduce1<<<RED1_BLKS, 256, 0, stream>>>(GRID_SL);
    reduce2<<<1, 256, 0, stream>>>(g3);
    pass4_slab<<<GRID_SL, 256, 0, stream>>>(g3, x, gated, out, nslabs4);
    final_local<<<128, 256, 0, stream>>>(lp, x, out + (size_t)nrows * D_DIM);
}